// Round 1
// baseline (142.223 us; speedup 1.0000x reference)
//
#include <hip/hip_runtime.h>
#include <stdint.h>
#include <stddef.h>

#define Tdim 4096
#define Hdim 2048

typedef short short8 __attribute__((ext_vector_type(8)));
typedef float floatx4 __attribute__((ext_vector_type(4)));

// RNE fp32 -> bf16 bit pattern
__device__ __forceinline__ unsigned short f2bf(float f) {
  uint32_t u = __float_as_uint(f);
  u += 0x7fffu + ((u >> 16) & 1u);
  return (unsigned short)(u >> 16);
}

// async global->LDS, 16B per lane. LDS dest is wave-uniform base + lane*16.
__device__ __forceinline__ void load_lds16(const void* g, void* l) {
  __builtin_amdgcn_global_load_lds(
      (__attribute__((address_space(1))) unsigned int*)(uintptr_t)g,
      (__attribute__((address_space(3))) unsigned int*)l,
      16, 0, 0);
}

__device__ __forceinline__ float tanh_fast(float z) {
  // tanh(z) = 1 - 2/(exp(2z)+1); safe for all z
  float e = __expf(z + z);
  return 1.0f - __fdividef(2.0f, e + 1.0f);
}

// aligned LDS vector read (forces ds_read_b128)
__device__ __forceinline__ short8 lds_read8(const unsigned short* p) {
  return *(const short8*)__builtin_assume_aligned(p, 16);
}

// ---- fused convert: blocks [0,4096) cast x -> bf16; blocks [4096,5120)
// transpose+cast b (HxH fp32, [k][n]) -> bt bf16 (N x K, [n][k]) ----
__global__ __launch_bounds__(256) void cvt_kernel(const float* __restrict__ x,
                                                  const float* __restrict__ b,
                                                  unsigned short* __restrict__ xbf,
                                                  unsigned short* __restrict__ bt) {
  __shared__ unsigned short tile[64 * 65];
  const int t = threadIdx.x;
  if (blockIdx.x < 4096) {
    size_t i = ((size_t)blockIdx.x * 256 + t) * 8;
    float4 f0 = *(const float4*)(x + i);
    float4 f1 = *(const float4*)(x + i + 4);
    union { unsigned short u[8]; uint4 v; } o;
    o.u[0] = f2bf(f0.x); o.u[1] = f2bf(f0.y); o.u[2] = f2bf(f0.z); o.u[3] = f2bf(f0.w);
    o.u[4] = f2bf(f1.x); o.u[5] = f2bf(f1.y); o.u[6] = f2bf(f1.z); o.u[7] = f2bf(f1.w);
    *(uint4*)(xbf + i) = o.v;
    return;
  }
  const int tb = blockIdx.x - 4096;
  const int bj = tb & 31;  // n block
  const int bi = tb >> 5;  // k block
  {
    const int r0 = t >> 4, c4 = (t & 15) * 4;
#pragma unroll
    for (int p = 0; p < 4; ++p) {
      int r = r0 + p * 16;
      float4 v = *(const float4*)(b + (size_t)(bi * 64 + r) * Hdim + bj * 64 + c4);
      tile[r * 65 + c4 + 0] = f2bf(v.x);
      tile[r * 65 + c4 + 1] = f2bf(v.y);
      tile[r * 65 + c4 + 2] = f2bf(v.z);
      tile[r * 65 + c4 + 3] = f2bf(v.w);
    }
  }
  __syncthreads();
  {
    const int n = t >> 2, kq = (t & 3) * 16;
    union { unsigned short u[16]; uint4 v[2]; } o;
#pragma unroll
    for (int q = 0; q < 16; ++q) o.u[q] = tile[(kq + q) * 65 + n];
    uint4* dst = (uint4*)(bt + (size_t)(bj * 64 + n) * Hdim + bi * 64 + kq);
    dst[0] = o.v[0];
    dst[1] = o.v[1];
  }
}

// ---- GEMM (s = x @ b) with fused windowed-scan epilogue ----
// Round 13: 8-phase-style counted-vmcnt pipeline (guide T3+T4+T5).
//
// BM=256 x BN=128, BK=64, 512 threads = 8 waves (4M x 2N, 64x64 per wave).
// Grid 16x16 = 256 blocks = 1/CU (LDS 147KB). Two phases per K-tile, each:
//   {8-9 ds_read_b128 || issue 3 global_load_lds for tile t+2}
//   s_barrier ; s_waitcnt lgkmcnt(0) ; sched_barrier ; setprio(1)
//   16 MFMA (+4 warm on waves 0,1) ; setprio(0) ; s_barrier
// 3 LDS buffers, 2-tile-deep prefetch. Per-wave counted waits, NEVER
// vmcnt(0) in steady state: per K-tile each thread issues 6 loads (wave 7:
// 7 incl. warm rows), so at each tile end outstanding = 2L; vmcnt(L)
// completes exactly tile t+1 and leaves tile t+2 in flight. Drain vmcnt(0)
// only at t=30. Rule-18 fence (sched_barrier(0)) after each lgkmcnt(0);
// raw barriers are asm with "memory" clobber so hipcc can't reorder
// LDS/DMA ops across them.
//
// LDS swizzle (proven in r12): slot (row, chunk c) holds global chunk
// c ^ (row&7); applied on the global fetch column (keeps global_load_lds
// dest linear); fragment reads XOR the same term. kk=0 chunk base
// c0=(quad^l7)*8, kk=32 is c0^32.
//
// XCD remap (bijective, 256%8==0): nid=(b&7)*32+(b>>3); bm=nid>>4,
// bn=nid&15 -> each XCD owns bm pair {2x,2x+1}: 2MB of A L2-resident,
// B panels stream from LLC.
//
// Warm rows: 8 extra A rows (t0-8..t0-1), staged by wave 7, MFMA'd by
// waves 0,1 (wn=0/64). Epilogue: acc -> s_tile (264x129 fp32, unioned
// with staging) -> 512 threads scan 128 cols x 4 chunks of 64 rows with
// 8-row in-tile warmup (|a|<=0.03125 -> window error < 1e-12).
#define BARM() asm volatile("s_barrier" ::: "memory")
#define WAITV(N) asm volatile("s_waitcnt vmcnt(" #N ")" ::: "memory")
#define WAITL0() asm volatile("s_waitcnt lgkmcnt(0)" ::: "memory")

__global__ __launch_bounds__(512, 2) void gemm_scan_kernel(const unsigned short* __restrict__ A,
                                                           const unsigned short* __restrict__ Bt,
                                                           const float* __restrict__ a_mat,
                                                           float* __restrict__ out) {
  // alignas(16) REQUIRED for short8 LDS reads to stay ds_read_b128.
  __shared__ alignas(16) union SM {
    struct {
      unsigned short sA[3][256 * 64];   // 3 x 32 KB
      unsigned short sB[3][128 * 64];   // 3 x 16 KB
      unsigned short sAw[3][8 * 64];    // 3 x 1 KB
    } st;                      // 147 KB
    float s_tile[264 * 129];   // 136 KB; [row][col], pad 129
  } sm;

  const int tid = threadIdx.x;
  const int b0 = blockIdx.x;
  const int nid = (b0 & 7) * 32 + (b0 >> 3);  // XCD-chunked remap
  const int bm = nid >> 4;                     // 0..15, tiles of 256 rows
  const int bn = nid & 15;                     // 0..15, tiles of 128 cols
  const int wave = tid >> 6, lane = tid & 63;
  const int wm = (wave >> 1) * 64, wn = (wave & 1) * 64;
  const int l15 = lane & 15, quad = lane >> 4;
  const int l7 = l15 & 7;

  // staging: thread tid fills LDS slot (row = tid>>3 + 64c, chunk = tid&7),
  // fetching global chunk (tid&7)^(row&7); row advances 64 (0 mod 8) per c,
  // so the XOR term is constant per thread.
  const int swz = ((tid & 7) ^ ((tid >> 3) & 7)) * 8;
  const unsigned short* aSrc = A + ((size_t)(bm * 256 + (tid >> 3)) * Hdim + swz);
  const unsigned short* bSrc = Bt + ((size_t)(bn * 128 + (tid >> 3)) * Hdim + swz);
  const int tw0 = (bm > 0) ? bm * 256 - 8 : 0;  // clamp keeps address valid
  const int wswz = ((lane & 7) ^ ((lane >> 3) & 7)) * 8;
  const unsigned short* wSrc = A + ((size_t)(tw0 + (lane >> 3)) * Hdim + wswz);

  floatx4 acc[4][4] = {};
  floatx4 accw[4] = {};

  const int c0 = (quad ^ l7) * 8;  // kk=0 chunk offset (shorts)
  const int c1 = c0 ^ 32;          // kk=32
  int rA[4], rB[4];
#pragma unroll
  for (int i = 0; i < 4; ++i) rA[i] = (wm + i * 16 + l15) * 64;
#pragma unroll
  for (int j = 0; j < 4; ++j) rB[j] = (wn + j * 16 + l15) * 64;

  // per-thread loads per K-tile: 3 in each phase (wave 7: +1 warm in p1)
  auto stage_p0 = [&](int nb, int k0) {
    unsigned short* aDst = &sm.st.sA[nb][tid * 8];
    load_lds16(aSrc + k0, aDst);
    load_lds16(aSrc + (size_t)64 * Hdim + k0, aDst + 4096);
    load_lds16(bSrc + k0, &sm.st.sB[nb][tid * 8]);
  };
  auto stage_p1 = [&](int nb, int k0) {
    unsigned short* aDst = &sm.st.sA[nb][tid * 8];
    load_lds16(aSrc + (size_t)128 * Hdim + k0, aDst + 8192);
    load_lds16(aSrc + (size_t)192 * Hdim + k0, aDst + 12288);
    load_lds16(bSrc + (size_t)64 * Hdim + k0, &sm.st.sB[nb][tid * 8 + 4096]);
    if (wave == 7) load_lds16(wSrc + k0, &sm.st.sAw[nb][lane * 8]);
  };

  // prologue: tiles 0,1 in flight; wait own tile-0 loads (leave tile 1's)
  stage_p0(0, 0);  stage_p1(0, 0);
  stage_p0(1, 64); stage_p1(1, 64);
  if (wave == 7) { WAITV(7); } else { WAITV(6); }
  BARM();

  int buf = 0;  // = t % 3
  for (int t = 0; t < 32; ++t) {
    const int nb = (buf >= 1) ? buf - 1 : 2;  // (t+2) % 3
    const bool pf = (t < 30);
    const int k2 = (t + 2) * 64;
    const unsigned short* sAb = sm.st.sA[buf];
    const unsigned short* sBb = sm.st.sB[buf];
    const unsigned short* sWb = sm.st.sAw[buf];

    short8 av[4], bv[4], aw = {};

    // ---- phase 0 : kk = 0..31 ----
#pragma unroll
    for (int i = 0; i < 4; ++i) av[i] = lds_read8(sAb + rA[i] + c0);
#pragma unroll
    for (int j = 0; j < 4; ++j) bv[j] = lds_read8(sBb + rB[j] + c0);
    if (wave < 2) aw = lds_read8(sWb + l7 * 64 + c0);
    if (pf) stage_p0(nb, k2);
    BARM();
    WAITL0();
    __builtin_amdgcn_sched_barrier(0);
    __builtin_amdgcn_s_setprio(1);
#pragma unroll
    for (int i = 0; i < 4; ++i)
#pragma unroll
      for (int j = 0; j < 4; ++j)
        acc[i][j] = __builtin_amdgcn_mfma_f32_16x16x32_bf16(av[i], bv[j], acc[i][j], 0, 0, 0);
    if (wave < 2) {
#pragma unroll
      for (int j = 0; j < 4; ++j)
        accw[j] = __builtin_amdgcn_mfma_f32_16x16x32_bf16(aw, bv[j], accw[j], 0, 0, 0);
    }
    __builtin_amdgcn_s_setprio(0);
    BARM();

    // ---- phase 1 : kk = 32..63 ----
#pragma unroll
    for (int i = 0; i < 4; ++i) av[i] = lds_read8(sAb + rA[i] + c1);
#pragma unroll
    for (int j = 0; j < 4; ++j) bv[j] = lds_read8(sBb + rB[j] + c1);
    if (wave < 2) aw = lds_read8(sWb + l7 * 64 + c1);
    if (pf) stage_p1(nb, k2);
    BARM();
    WAITL0();
    __builtin_amdgcn_sched_barrier(0);
    __builtin_amdgcn_s_setprio(1);
#pragma unroll
    for (int i = 0; i < 4; ++i)
#pragma unroll
      for (int j = 0; j < 4; ++j)
        acc[i][j] = __builtin_amdgcn_mfma_f32_16x16x32_bf16(av[i], bv[j], acc[i][j], 0, 0, 0);
    if (wave < 2) {
#pragma unroll
      for (int j = 0; j < 4; ++j)
        accw[j] = __builtin_amdgcn_mfma_f32_16x16x32_bf16(aw, bv[j], accw[j], 0, 0, 0);
    }
    __builtin_amdgcn_s_setprio(0);
    // tile-boundary wait: complete tile t+1, keep tile t+2 in flight
    if (t < 30) {
      if (wave == 7) { WAITV(7); } else { WAITV(6); }
    } else if (t == 30) {
      WAITV(0);
    }
    BARM();
    buf = (buf == 2) ? 0 : buf + 1;
  }
  __syncthreads();  // safety before LDS union repurpose (all counters 0 here)

  // ---- epilogue: registers -> s_tile (C/D layout: col=lane&15, row=quad*4+r) ----
  if (wave < 2 && quad < 2) {  // warm rows idx 0..7
#pragma unroll
    for (int j = 0; j < 4; ++j)
#pragma unroll
      for (int r = 0; r < 4; ++r)
        sm.s_tile[(quad * 4 + r) * 129 + wn + j * 16 + l15] = accw[j][r];
  }
#pragma unroll
  for (int i = 0; i < 4; ++i)
#pragma unroll
    for (int j = 0; j < 4; ++j)
#pragma unroll
      for (int r = 0; r < 4; ++r)
        sm.s_tile[(8 + wm + i * 16 + quad * 4 + r) * 129 + wn + j * 16 + l15] = acc[i][j][r];
  __syncthreads();

  // ---- windowed scan: 512 threads = 128 cols x 4 chunks of 64 rows ----
  const int col = tid & 127;
  const int chunk = tid >> 7;
  const float aj = a_mat[bn * 128 + col];
  float h = 0.0f;
  const int row0 = 8 + chunk * 64;
  if (!(bm == 0 && chunk == 0)) {
#pragma unroll
    for (int r = row0 - 8; r < row0; ++r)  // warm-up (discarded outputs)
      h = tanh_fast(fmaf(aj, h, sm.s_tile[r * 129 + col]));
  }
  const size_t gbase = (size_t)(bm * 256 + chunk * 64) * Hdim + bn * 128 + col;
#pragma unroll 4
  for (int r2 = 0; r2 < 64; ++r2) {
    h = tanh_fast(fmaf(aj, h, sm.s_tile[(row0 + r2) * 129 + col]));
    out[gbase + (size_t)r2 * Hdim] = h;
  }
}

extern "C" void kernel_launch(void* const* d_in, const int* in_sizes, int n_in,
                              void* d_out, int out_size, void* d_ws, size_t ws_size,
                              hipStream_t stream) {
  const float* x = (const float*)d_in[0];
  const float* a = (const float*)d_in[1];
  const float* b = (const float*)d_in[2];
  float* out = (float*)d_out;

  unsigned short* ws = (unsigned short*)d_ws;
  unsigned short* xbf = ws;                                 // 16.8 MB
  unsigned short* btb = xbf + (size_t)Tdim * Hdim;          // 8.4 MB

  hipLaunchKernelGGL(cvt_kernel, dim3(4096 + (Hdim / 64) * (Hdim / 64)), dim3(256), 0, stream,
                     x, b, xbf, btb);
  hipLaunchKernelGGL(gemm_scan_kernel, dim3((Tdim / 256) * (Hdim / 128)), dim3(512), 0, stream,
                     xbf, btb, a, out);
}